// Round 13
// baseline (386.930 us; speedup 1.0000x reference)
//
#include <hip/hip_runtime.h>
#include <hip/hip_bf16.h>

// Fused CausalSelfAttention: x @ Wa^T + ba -> split heads -> causal flash attn
// -> y @ Wp^T + bp.  B=4, T=2048, C=768, H=12, hs=64.  bf16 MFMA, fp32 accum.
//
// ws (shorts): xb[8192*768] wab[2304*768] wpb[768*768] qkvb[8192*2304] yb[8192*768]
//              vtb[48*64*2048]  (~80 MB)

typedef __attribute__((ext_vector_type(8))) short bf16x8;
typedef __attribute__((ext_vector_type(4))) short bf16x4;
typedef __attribute__((ext_vector_type(4))) float f32x4;

#define MFMA16(a, b, c) __builtin_amdgcn_mfma_f32_16x16x32_bf16((a), (b), (c), 0, 0, 0)

__device__ __forceinline__ unsigned short f2bfbits(float f) {
  return __builtin_bit_cast(unsigned short, __float2bfloat16(f));
}
__device__ __forceinline__ float bf2f(short b) {
  return __uint_as_float(((unsigned)(unsigned short)b) << 16);
}
__device__ __forceinline__ float fast_exp2(float x) {
#if __has_builtin(__builtin_amdgcn_exp2f)
  return __builtin_amdgcn_exp2f(x);
#else
  return __expf(x * 0.6931471805599453f);
#endif
}
__device__ __forceinline__ float fmax3(float a, float b, float c) {
  return fmaxf(fmaxf(a, b), c);  // clang fuses to v_max3_f32
}
// truncation-pack two fp32 -> one u32 of 2 bf16 (RTZ; P is ratio-normalized so bias cancels)
__device__ __forceinline__ unsigned pk2bf(float lo, float hi) {
  return (__builtin_bit_cast(unsigned, hi) & 0xffff0000u) |
         (__builtin_bit_cast(unsigned, lo) >> 16);
}

__device__ __forceinline__ void gload_lds16(const void* g, void* l) {
  __builtin_amdgcn_global_load_lds((const __attribute__((address_space(1))) void*)g,
                                   (__attribute__((address_space(3))) void*)l, 16, 0, 0);
}

// ---------------- fp32 -> bf16 convert (x, w_attn, w_proj fused) ----------------
__global__ __launch_bounds__(256) void cvt3(const float* __restrict__ x,
                                            const float* __restrict__ wa,
                                            const float* __restrict__ wp,
                                            unsigned short* __restrict__ xb,
                                            unsigned short* __restrict__ wab,
                                            unsigned short* __restrict__ wpb) {
  int i = blockIdx.x * 256 + threadIdx.x;
  const float* in;
  unsigned short* out;
  int j;
  if (i < 1572864) { in = x; out = xb; j = i; }
  else if (i < 2015232) { in = wa; out = wab; j = i - 1572864; }
  else { in = wp; out = wpb; j = i - 2015232; }
  float4 f = ((const float4*)in)[j];
  bf16x4 o;
  o[0] = (short)f2bfbits(f.x); o[1] = (short)f2bfbits(f.y);
  o[2] = (short)f2bfbits(f.z); o[3] = (short)f2bfbits(f.w);
  ((bf16x4*)out)[j] = o;
}

// ---------------- GEMM (m97 + chunk-XOR swizzle + T1 XCD block swizzle) ----------------
// 1D grid (nwg = 8*cpx), swz = (bid&7)*cpx + bid>>3; bx = swz % nx (x-inner).
template <typename OutT>
__global__ __launch_bounds__(256) void gemm_bt(const unsigned short* __restrict__ A,
                                               const unsigned short* __restrict__ Bt,
                                               const float* __restrict__ bias,
                                               OutT* __restrict__ C, int M, int N, int K,
                                               int nx, int cpx) {
  __shared__ unsigned short As[128 * 64];
  __shared__ unsigned short Bs[128 * 64];
  const int tid = threadIdx.x;
  const int w = tid >> 6, l = tid & 63;
  const int g = l >> 4, li = l & 15;
  const int wm = w >> 1, wn = w & 1;

  const int bid = blockIdx.x;
  const int swz = (bid & 7) * cpx + (bid >> 3);   // bijective (nwg % 8 == 0)
  const int bx = swz % nx, by = swz / nx;
  const int m0 = by * 128, n0 = bx * 128;

  const int scw = (l & 7) ^ ((l >> 3) & 7);
  const int swr = li & 7;

  f32x4 acc[4][4] = {};

  for (int kt = 0; kt < K; kt += 64) {
#pragma unroll
    for (int n = 0; n < 4; ++n) {
      int R = w * 32 + n * 8 + (l >> 3);
      gload_lds16(A + (long)(m0 + R) * K + kt + scw * 8, &As[(w * 32 + n * 8) * 64]);
      gload_lds16(Bt + (long)(n0 + R) * K + kt + scw * 8, &Bs[(w * 32 + n * 8) * 64]);
    }
    __syncthreads();
#pragma unroll
    for (int kk = 0; kk < 2; ++kk) {
      bf16x8 a[4], b[4];
#pragma unroll
      for (int m = 0; m < 4; ++m)
        a[m] = *(const bf16x8*)&As[(wm * 64 + m * 16 + li) * 64 + ((kk * 4 + g) ^ swr) * 8];
#pragma unroll
      for (int n = 0; n < 4; ++n)
        b[n] = *(const bf16x8*)&Bs[(wn * 64 + n * 16 + li) * 64 + ((kk * 4 + g) ^ swr) * 8];
#pragma unroll
      for (int m = 0; m < 4; ++m)
#pragma unroll
        for (int n = 0; n < 4; ++n) acc[m][n] = MFMA16(a[m], b[n], acc[m][n]);
    }
    __syncthreads();
  }

#pragma unroll
  for (int m = 0; m < 4; ++m) {
    int row = m0 + wm * 64 + m * 16 + 4 * g;
#pragma unroll
    for (int n = 0; n < 4; ++n) {
      int col = n0 + wn * 64 + n * 16 + li;
      float bi = bias[col];
#pragma unroll
      for (int r = 0; r < 4; ++r) {
        float v = acc[m][n][r] + bi;
        if constexpr (sizeof(OutT) == 2)
          C[(long)(row + r) * N + col] = (OutT)f2bfbits(v);
        else
          C[(long)(row + r) * N + col] = v;
      }
    }
  }
}

// ---------------- V transpose: qkv V-part -> Vt[bh][d][t] ----------------
__global__ __launch_bounds__(64) void transpose_v(const unsigned short* __restrict__ qkv,
                                                  unsigned short* __restrict__ vt) {
  const int kt = blockIdx.x & 31, bh = blockIdx.x >> 5;
  const int b = bh / 12, h = bh - b * 12;
  const int l = threadIdx.x;
  const int ct = l & 7, cd = l >> 3;

  bf16x8 tin[8], tout[8];
#pragma unroll
  for (int i = 0; i < 8; ++i)
    tin[i] = *(const bf16x8*)(qkv + (long)(b * 2048 + kt * 64 + ct * 8 + i) * 2304 +
                              1536 + h * 64 + cd * 8);
#pragma unroll
  for (int j = 0; j < 8; ++j) {
#pragma unroll
    for (int i = 0; i < 8; ++i) tout[j][i] = tin[i][j];
    *(bf16x8*)(vt + (long)(bh * 64 + cd * 8 + j) * 2048 + kt * 64 + ct * 8) = tout[j];
  }
}

// ---------------- attention helpers ----------------
__device__ __forceinline__ bf16x8 scale_bf8(bf16x8 v, float c) {
  bf16x8 o;
#pragma unroll
  for (int j = 0; j < 8; ++j) o[j] = (short)f2bfbits(bf2f(v[j]) * c);
  return o;
}

// softmax of one 64(k)x16(q) S^T state (log2 domain); P (bf16, RTZ) -> LDS.
// Row-sum l comes from the ones-column MFMA in PV (o4).
__device__ __forceinline__ void softmax_state(f32x4* s, bool diag, int g, int li, int qloc,
                                              unsigned short* PsW, float& m, f32x4* o,
                                              f32x4& o4) {
  if (diag) {
#pragma unroll
    for (int kn = 0; kn < 4; ++kn)
#pragma unroll
      for (int r = 0; r < 4; ++r)
        if (kn * 16 + 4 * g + r > qloc) s[kn][r] = -1e30f;
  }
  float a = fmax3(s[0][0], s[0][1], s[0][2]);
  float b = fmax3(s[0][3], s[1][0], s[1][1]);
  float c = fmax3(s[1][2], s[1][3], s[2][0]);
  float d = fmax3(s[2][1], s[2][2], s[2][3]);
  float e = fmax3(s[3][0], s[3][1], s[3][2]);
  float pm = fmaxf(fmax3(a, b, c), fmax3(d, e, s[3][3]));
  pm = fmaxf(pm, __shfl_xor(pm, 16));
  pm = fmaxf(pm, __shfl_xor(pm, 32));

  if (!__all(pm - m <= 10.0f)) {  // defer-max (T13): rescale only on real growth
    float mn = fmaxf(m, pm);
    float alpha = fast_exp2(m - mn);
    m = mn;
    float alo[4];
#pragma unroll
    for (int r = 0; r < 4; ++r) alo[r] = __shfl(alpha, 20 * g + r);
#pragma unroll
    for (int dn = 0; dn < 4; ++dn)
#pragma unroll
      for (int r = 0; r < 4; ++r) o[dn][r] *= alo[r];
#pragma unroll
    for (int r = 0; r < 4; ++r) o4[r] *= alo[r];
  }

  const int swp = li & 7;
#pragma unroll
  for (int kn = 0; kn < 4; ++kn) {
    float e0 = fast_exp2(s[kn][0] - m);
    float e1 = fast_exp2(s[kn][1] - m);
    float e2 = fast_exp2(s[kn][2] - m);
    float e3 = fast_exp2(s[kn][3] - m);
    uint2 pk = {pk2bf(e0, e1), pk2bf(e2, e3)};
    *(uint2*)&PsW[li * 64 + ((kn * 2 + (g >> 1)) ^ swp) * 8 + (g & 1) * 4] = pk;
  }
}

// one full state: QK (K from LDS) -> softmax -> PV (V from registers, loaded from L2).
// Same-wave LDS ops are in-order, so sm's ds_write is seen by PV's ds_read w/o fence.
__device__ __forceinline__ void attn_state(const unsigned short* Ks, const bf16x8* vb,
                                           unsigned short* PsW, const bf16x8* bq, bool diag,
                                           int g, int li, int qloc,
                                           float& m, f32x4* o, f32x4& o4) {
  f32x4 s[4];
  __builtin_amdgcn_s_setprio(1);
#pragma unroll
  for (int kn = 0; kn < 4; ++kn) {
    int rr = kn * 16 + li, sw = rr & 7;
    f32x4 acc = {};
#pragma unroll
    for (int kk = 0; kk < 2; ++kk) {
      bf16x8 ak = *(const bf16x8*)&Ks[rr * 64 + ((kk * 4 + g) ^ sw) * 8];
      acc = MFMA16(ak, bq[kk], acc);
    }
    s[kn] = acc;
  }
  __builtin_amdgcn_s_setprio(0);

  softmax_state(s, diag, g, li, qloc, PsW, m, o, o4);

  bf16x8 vones;
#pragma unroll
  for (int j = 0; j < 8; ++j) vones[j] = (short)0x3F80;
  const int swp = li & 7;
  __builtin_amdgcn_s_setprio(1);
#pragma unroll
  for (int kk = 0; kk < 2; ++kk) {
    bf16x8 pa = *(const bf16x8*)&PsW[li * 64 + ((kk * 4 + g) ^ swp) * 8];
#pragma unroll
    for (int dn = 0; dn < 4; ++dn) o[dn] = MFMA16(pa, vb[kk * 4 + dn], o[dn]);
    o4 = MFMA16(pa, vones, o4);   // row-sum l via ones column
  }
  __builtin_amdgcn_s_setprio(0);
}

// ---------------- causal flash attention (paired q-tiles, V direct from L2) ----------------
// LDS = Ks dbuf 16 KB + Ps 8 KB = 24 KB -> 6 blocks/CU.  V fragments are q-independent:
// loaded once per iteration into registers, shared by both states (m169: don't LDS-stage
// L2-resident data).  vb loads issued BEFORE the K prefetch so PV's auto-vmcnt leaves the
// (newer) prefetch in flight.
__global__ __launch_bounds__(256, 6) void attn_fwd(const unsigned short* __restrict__ qkv,
                                                   const unsigned short* __restrict__ vt,
                                                   unsigned short* __restrict__ y) {
  const int xcd = blockIdx.x & 7;
  const int slot = blockIdx.x >> 3;                       // 0..95
  const int bh = xcd * 6 + (slot >> 4);                   // XCD-local bh (L2 locality)
  const int p = ((slot & 15) + 11 * (slot >> 5)) & 15;    // decorrelated pair index
  const int b = bh / 12, h = bh - b * 12;
  const int qlo = p, qhi = 31 - p;
  const int tid = threadIdx.x;
  const int w = tid >> 6, l = tid & 63;
  const int g = l >> 4, li = l & 15;
  const int qloc = w * 16 + li;

  __shared__ unsigned short Ks[2][64 * 64];
  __shared__ unsigned short Ps[4][16 * 64];   // one buffer per wave (H then L)
  unsigned short* PsW = &Ps[w][0];

  const unsigned short* base = qkv + (long)b * 2048 * 2304;

  // Q fragments (B-operand), pre-scaled by 0.125*log2(e) -> softmax in exp2 domain
  const float QS = 0.18033688011112042f;
  bf16x8 bqlo[2], bqhi[2];
  {
    const unsigned short* qr = base + (long)(qlo * 64 + qloc) * 2304 + h * 64;
    bqlo[0] = scale_bf8(*(const bf16x8*)(qr + 8 * g), QS);
    bqlo[1] = scale_bf8(*(const bf16x8*)(qr + 32 + 8 * g), QS);
    qr = base + (long)(qhi * 64 + qloc) * 2304 + h * 64;
    bqhi[0] = scale_bf8(*(const bf16x8*)(qr + 8 * g), QS);
    bqhi[1] = scale_bf8(*(const bf16x8*)(qr + 32 + 8 * g), QS);
  }

  float m_lo = -1e30f, m_hi = -1e30f;
  f32x4 o_lo[4] = {}, o_hi[4] = {};
  f32x4 o4_lo = {}, o4_hi = {};

  const int sR = w * 8 + (l >> 3);
  const int sc = l & 7;
  // V fragment base: lane (g,li) reads rows d = dn*16+li, cols kt*64 + kk*32 + 8g
  const unsigned short* vbase = vt + (long)(bh * 64 + li) * 2048 + 8 * g;

  int buf = 0;
  {
#pragma unroll
    for (int n = 0; n < 2; ++n) {
      int R = n * 32 + sR;
      int c = sc ^ (R & 7);
      gload_lds16(base + (long)R * 2304 + 768 + h * 64 + c * 8, &Ks[0][(n * 32 + w * 8) * 64]);
    }
  }
  __syncthreads();

  for (int kt = 0; kt <= qhi; ++kt) {
    // V fragments for this tile (global, L2-hit) -- issue FIRST (older than prefetch)
    bf16x8 vb[8];
#pragma unroll
    for (int kk = 0; kk < 2; ++kk)
#pragma unroll
      for (int dn = 0; dn < 4; ++dn)
        vb[kk * 4 + dn] = *(const bf16x8*)(vbase + (long)dn * 32768 + kt * 64 + kk * 32);

    if (kt < qhi) {
#pragma unroll
      for (int n = 0; n < 2; ++n) {
        int R = n * 32 + sR;
        int c = sc ^ (R & 7);
        gload_lds16(base + (long)((kt + 1) * 64 + R) * 2304 + 768 + h * 64 + c * 8,
                    &Ks[buf ^ 1][(n * 32 + w * 8) * 64]);
      }
    }
    attn_state(Ks[buf], vb, PsW, bqhi, kt == qhi, g, li, qloc, m_hi, o_hi, o4_hi);
    if (kt <= qlo)
      attn_state(Ks[buf], vb, PsW, bqlo, kt == qlo, g, li, qloc, m_lo, o_lo, o4_lo);
    __syncthreads();  // drains vmcnt (prefetch) + lgkm; protects buf swap
    buf ^= 1;
  }

#pragma unroll
  for (int t = 0; t < 2; ++t) {
    const f32x4* o = t ? o_hi : o_lo;
    const f32x4& o4 = t ? o4_hi : o4_lo;
    int qt = t ? qhi : qlo;
#pragma unroll
    for (int r = 0; r < 4; ++r) {
      float inv = 1.0f / o4[r];  // same q-domain as o: no shfl needed
      long row = (long)b * 2048 + qt * 64 + w * 16 + 4 * g + r;
#pragma unroll
      for (int dn = 0; dn < 4; ++dn)
        y[row * 768 + h * 64 + dn * 16 + li] = (unsigned short)f2bfbits(o[dn][r] * inv);
    }
  }
}

// ---------------- launch ----------------
extern "C" void kernel_launch(void* const* d_in, const int* in_sizes, int n_in,
                              void* d_out, int out_size, void* d_ws, size_t ws_size,
                              hipStream_t stream) {
  const float* x      = (const float*)d_in[0];
  const float* w_attn = (const float*)d_in[1];
  const float* b_attn = (const float*)d_in[2];
  const float* w_proj = (const float*)d_in[3];
  const float* b_proj = (const float*)d_in[4];
  float* out = (float*)d_out;

  unsigned short* xb   = (unsigned short*)d_ws;
  unsigned short* wab  = xb + 6291456;                  // 8192*768
  unsigned short* wpb  = wab + 1769472;                 // 2304*768
  unsigned short* qkvb = wpb + 589824;                  // 768*768
  unsigned short* yb   = qkvb + (long)8192 * 2304;
  unsigned short* vtb  = yb + 6291456;                  // 48*64*2048

  cvt3<<<8448, 256, 0, stream>>>(x, w_attn, w_proj, xb, wab, wpb);

  // QKV: 18x64 tiles -> 1152 blocks (8*144); x-inner XCD swizzle
  gemm_bt<unsigned short><<<1152, 256, 0, stream>>>(xb, wab, b_attn, qkvb, 8192, 2304, 768, 18, 144);
  transpose_v<<<1536, 64, 0, stream>>>(qkvb, vtb);
  attn_fwd<<<768, 256, 0, stream>>>(qkvb, vtb, yb);
  // proj: 6x64 tiles -> 384 blocks (8*48)
  gemm_bt<float><<<384, 256, 0, stream>>>(yb, wpb, b_proj, out, 8192, 768, 768, 6, 48);
}

// Round 14
// 191.566 us; speedup vs baseline: 2.0198x; 2.0198x over previous
//
#include <hip/hip_runtime.h>
#include <hip/hip_bf16.h>

// Fused CausalSelfAttention: x @ Wa^T + ba -> split heads -> causal flash attn
// -> y @ Wp^T + bp.  B=4, T=2048, C=768, H=12, hs=64.  bf16 MFMA, fp32 accum.
//
// ws (shorts): xb[8192*768] wab[2304*768] wpb[768*768] qkvb[8192*2304] yb[8192*768]
//              vtb[48*64*2048]  (~80 MB)

typedef __attribute__((ext_vector_type(8))) short bf16x8;
typedef __attribute__((ext_vector_type(4))) short bf16x4;
typedef __attribute__((ext_vector_type(4))) float f32x4;

#define MFMA16(a, b, c) __builtin_amdgcn_mfma_f32_16x16x32_bf16((a), (b), (c), 0, 0, 0)

__device__ __forceinline__ unsigned short f2bfbits(float f) {
  return __builtin_bit_cast(unsigned short, __float2bfloat16(f));
}
__device__ __forceinline__ float bf2f(short b) {
  return __uint_as_float(((unsigned)(unsigned short)b) << 16);
}
__device__ __forceinline__ float fast_exp2(float x) {
#if __has_builtin(__builtin_amdgcn_exp2f)
  return __builtin_amdgcn_exp2f(x);
#else
  return __expf(x * 0.6931471805599453f);
#endif
}
__device__ __forceinline__ float fmax3(float a, float b, float c) {
  return fmaxf(fmaxf(a, b), c);  // clang fuses to v_max3_f32
}
// truncation-pack two fp32 -> one u32 of 2 bf16 (RTZ; P is ratio-normalized so bias cancels)
__device__ __forceinline__ unsigned pk2bf(float lo, float hi) {
  return (__builtin_bit_cast(unsigned, hi) & 0xffff0000u) |
         (__builtin_bit_cast(unsigned, lo) >> 16);
}

__device__ __forceinline__ void gload_lds16(const void* g, void* l) {
  __builtin_amdgcn_global_load_lds((const __attribute__((address_space(1))) void*)g,
                                   (__attribute__((address_space(3))) void*)l, 16, 0, 0);
}

// ---------------- fp32 -> bf16 convert (x, w_attn, w_proj fused) ----------------
__global__ __launch_bounds__(256) void cvt3(const float* __restrict__ x,
                                            const float* __restrict__ wa,
                                            const float* __restrict__ wp,
                                            unsigned short* __restrict__ xb,
                                            unsigned short* __restrict__ wab,
                                            unsigned short* __restrict__ wpb) {
  int i = blockIdx.x * 256 + threadIdx.x;
  const float* in;
  unsigned short* out;
  int j;
  if (i < 1572864) { in = x; out = xb; j = i; }
  else if (i < 2015232) { in = wa; out = wab; j = i - 1572864; }
  else { in = wp; out = wpb; j = i - 2015232; }
  float4 f = ((const float4*)in)[j];
  bf16x4 o;
  o[0] = (short)f2bfbits(f.x); o[1] = (short)f2bfbits(f.y);
  o[2] = (short)f2bfbits(f.z); o[3] = (short)f2bfbits(f.w);
  ((bf16x4*)out)[j] = o;
}

// ---------------- GEMM (m97 + chunk-XOR swizzle + T1 XCD block swizzle) ----------------
// 1D grid (nwg = 8*cpx), swz = (bid&7)*cpx + bid>>3; bx = swz % nx (x-inner).
template <typename OutT>
__global__ __launch_bounds__(256) void gemm_bt(const unsigned short* __restrict__ A,
                                               const unsigned short* __restrict__ Bt,
                                               const float* __restrict__ bias,
                                               OutT* __restrict__ C, int M, int N, int K,
                                               int nx, int cpx) {
  __shared__ unsigned short As[128 * 64];
  __shared__ unsigned short Bs[128 * 64];
  const int tid = threadIdx.x;
  const int w = tid >> 6, l = tid & 63;
  const int g = l >> 4, li = l & 15;
  const int wm = w >> 1, wn = w & 1;

  const int bid = blockIdx.x;
  const int swz = (bid & 7) * cpx + (bid >> 3);   // bijective (nwg % 8 == 0)
  const int bx = swz % nx, by = swz / nx;
  const int m0 = by * 128, n0 = bx * 128;

  const int scw = (l & 7) ^ ((l >> 3) & 7);
  const int swr = li & 7;

  f32x4 acc[4][4] = {};

  for (int kt = 0; kt < K; kt += 64) {
#pragma unroll
    for (int n = 0; n < 4; ++n) {
      int R = w * 32 + n * 8 + (l >> 3);
      gload_lds16(A + (long)(m0 + R) * K + kt + scw * 8, &As[(w * 32 + n * 8) * 64]);
      gload_lds16(Bt + (long)(n0 + R) * K + kt + scw * 8, &Bs[(w * 32 + n * 8) * 64]);
    }
    __syncthreads();
#pragma unroll
    for (int kk = 0; kk < 2; ++kk) {
      bf16x8 a[4], b[4];
#pragma unroll
      for (int m = 0; m < 4; ++m)
        a[m] = *(const bf16x8*)&As[(wm * 64 + m * 16 + li) * 64 + ((kk * 4 + g) ^ swr) * 8];
#pragma unroll
      for (int n = 0; n < 4; ++n)
        b[n] = *(const bf16x8*)&Bs[(wn * 64 + n * 16 + li) * 64 + ((kk * 4 + g) ^ swr) * 8];
#pragma unroll
      for (int m = 0; m < 4; ++m)
#pragma unroll
        for (int n = 0; n < 4; ++n) acc[m][n] = MFMA16(a[m], b[n], acc[m][n]);
    }
    __syncthreads();
  }

#pragma unroll
  for (int m = 0; m < 4; ++m) {
    int row = m0 + wm * 64 + m * 16 + 4 * g;
#pragma unroll
    for (int n = 0; n < 4; ++n) {
      int col = n0 + wn * 64 + n * 16 + li;
      float bi = bias[col];
#pragma unroll
      for (int r = 0; r < 4; ++r) {
        float v = acc[m][n][r] + bi;
        if constexpr (sizeof(OutT) == 2)
          C[(long)(row + r) * N + col] = (OutT)f2bfbits(v);
        else
          C[(long)(row + r) * N + col] = v;
      }
    }
  }
}

// ---------------- V transpose: qkv V-part -> Vt[bh][d][t] ----------------
__global__ __launch_bounds__(64) void transpose_v(const unsigned short* __restrict__ qkv,
                                                  unsigned short* __restrict__ vt) {
  const int kt = blockIdx.x & 31, bh = blockIdx.x >> 5;
  const int b = bh / 12, h = bh - b * 12;
  const int l = threadIdx.x;
  const int ct = l & 7, cd = l >> 3;

  bf16x8 tin[8], tout[8];
#pragma unroll
  for (int i = 0; i < 8; ++i)
    tin[i] = *(const bf16x8*)(qkv + (long)(b * 2048 + kt * 64 + ct * 8 + i) * 2304 +
                              1536 + h * 64 + cd * 8);
#pragma unroll
  for (int j = 0; j < 8; ++j) {
#pragma unroll
    for (int i = 0; i < 8; ++i) tout[j][i] = tin[i][j];
    *(bf16x8*)(vt + (long)(bh * 64 + cd * 8 + j) * 2048 + kt * 64 + ct * 8) = tout[j];
  }
}

// ---------------- attention helpers ----------------
__device__ __forceinline__ bf16x8 scale_bf8(bf16x8 v, float c) {
  bf16x8 o;
#pragma unroll
  for (int j = 0; j < 8; ++j) o[j] = (short)f2bfbits(bf2f(v[j]) * c);
  return o;
}

// softmax of one 64(k)x16(q) S^T state (log2 domain); P (bf16, RTZ) -> LDS.
// Row-sum l comes from the ones-column MFMA in PV (o4).
__device__ __forceinline__ void softmax_state(f32x4* s, bool diag, int g, int li, int qloc,
                                              unsigned short* PsW, float& m, f32x4* o,
                                              f32x4& o4) {
  if (diag) {
#pragma unroll
    for (int kn = 0; kn < 4; ++kn)
#pragma unroll
      for (int r = 0; r < 4; ++r)
        if (kn * 16 + 4 * g + r > qloc) s[kn][r] = -1e30f;
  }
  float a = fmax3(s[0][0], s[0][1], s[0][2]);
  float b = fmax3(s[0][3], s[1][0], s[1][1]);
  float c = fmax3(s[1][2], s[1][3], s[2][0]);
  float d = fmax3(s[2][1], s[2][2], s[2][3]);
  float e = fmax3(s[3][0], s[3][1], s[3][2]);
  float pm = fmaxf(fmax3(a, b, c), fmax3(d, e, s[3][3]));
  pm = fmaxf(pm, __shfl_xor(pm, 16));
  pm = fmaxf(pm, __shfl_xor(pm, 32));

  if (!__all(pm - m <= 10.0f)) {  // defer-max (T13): rescale only on real growth
    float mn = fmaxf(m, pm);
    float alpha = fast_exp2(m - mn);
    m = mn;
    float alo[4];
#pragma unroll
    for (int r = 0; r < 4; ++r) alo[r] = __shfl(alpha, 20 * g + r);
#pragma unroll
    for (int dn = 0; dn < 4; ++dn)
#pragma unroll
      for (int r = 0; r < 4; ++r) o[dn][r] *= alo[r];
#pragma unroll
    for (int r = 0; r < 4; ++r) o4[r] *= alo[r];
  }

  const int swp = li & 7;
#pragma unroll
  for (int kn = 0; kn < 4; ++kn) {
    float e0 = fast_exp2(s[kn][0] - m);
    float e1 = fast_exp2(s[kn][1] - m);
    float e2 = fast_exp2(s[kn][2] - m);
    float e3 = fast_exp2(s[kn][3] - m);
    uint2 pk = {pk2bf(e0, e1), pk2bf(e2, e3)};
    *(uint2*)&PsW[li * 64 + ((kn * 2 + (g >> 1)) ^ swp) * 8 + (g & 1) * 4] = pk;
  }
}

// one full state: QK (K from LDS) -> softmax -> PV (V from registers, loaded from L2).
// Same-wave LDS ops are in-order, so sm's ds_write is seen by PV's ds_read w/o fence.
__device__ __forceinline__ void attn_state(const unsigned short* Ks, const bf16x8* vb,
                                           unsigned short* PsW, const bf16x8* bq, bool diag,
                                           int g, int li, int qloc,
                                           float& m, f32x4* o, f32x4& o4) {
  f32x4 s[4];
  __builtin_amdgcn_s_setprio(1);
#pragma unroll
  for (int kn = 0; kn < 4; ++kn) {
    int rr = kn * 16 + li, sw = rr & 7;
    f32x4 acc = {};
#pragma unroll
    for (int kk = 0; kk < 2; ++kk) {
      bf16x8 ak = *(const bf16x8*)&Ks[rr * 64 + ((kk * 4 + g) ^ sw) * 8];
      acc = MFMA16(ak, bq[kk], acc);
    }
    s[kn] = acc;
  }
  __builtin_amdgcn_s_setprio(0);

  softmax_state(s, diag, g, li, qloc, PsW, m, o, o4);

  bf16x8 vones;
#pragma unroll
  for (int j = 0; j < 8; ++j) vones[j] = (short)0x3F80;
  const int swp = li & 7;
  __builtin_amdgcn_s_setprio(1);
#pragma unroll
  for (int kk = 0; kk < 2; ++kk) {
    bf16x8 pa = *(const bf16x8*)&PsW[li * 64 + ((kk * 4 + g) ^ swp) * 8];
#pragma unroll
    for (int dn = 0; dn < 4; ++dn) o[dn] = MFMA16(pa, vb[kk * 4 + dn], o[dn]);
    o4 = MFMA16(pa, vones, o4);   // row-sum l via ones column
  }
  __builtin_amdgcn_s_setprio(0);
}

// ---------------- causal flash attention (paired q-tiles, V direct from L2) ----------------
// LDS = Ks dbuf 16 KB + Ps 8 KB = 24 KB.  V fragments are q-independent: loaded once per
// iteration into registers, shared by both states (m169: don't LDS-stage L2-resident data).
// vb loads issued BEFORE the K prefetch so PV's auto-vmcnt leaves the prefetch in flight.
// NOTE __launch_bounds__ 2nd arg = min waves per EU: 4 -> 128-VGPR budget.  R13's value
// of 6 capped the allocator at ~85 VGPRs and caused a catastrophic scratch spill.
__global__ __launch_bounds__(256, 4) void attn_fwd(const unsigned short* __restrict__ qkv,
                                                   const unsigned short* __restrict__ vt,
                                                   unsigned short* __restrict__ y) {
  const int xcd = blockIdx.x & 7;
  const int slot = blockIdx.x >> 3;                       // 0..95
  const int bh = xcd * 6 + (slot >> 4);                   // XCD-local bh (L2 locality)
  const int p = ((slot & 15) + 11 * (slot >> 5)) & 15;    // decorrelated pair index
  const int b = bh / 12, h = bh - b * 12;
  const int qlo = p, qhi = 31 - p;
  const int tid = threadIdx.x;
  const int w = tid >> 6, l = tid & 63;
  const int g = l >> 4, li = l & 15;
  const int qloc = w * 16 + li;

  __shared__ unsigned short Ks[2][64 * 64];
  __shared__ unsigned short Ps[4][16 * 64];   // one buffer per wave (H then L)
  unsigned short* PsW = &Ps[w][0];

  const unsigned short* base = qkv + (long)b * 2048 * 2304;

  // Q fragments (B-operand), pre-scaled by 0.125*log2(e) -> softmax in exp2 domain
  const float QS = 0.18033688011112042f;
  bf16x8 bqlo[2], bqhi[2];
  {
    const unsigned short* qr = base + (long)(qlo * 64 + qloc) * 2304 + h * 64;
    bqlo[0] = scale_bf8(*(const bf16x8*)(qr + 8 * g), QS);
    bqlo[1] = scale_bf8(*(const bf16x8*)(qr + 32 + 8 * g), QS);
    qr = base + (long)(qhi * 64 + qloc) * 2304 + h * 64;
    bqhi[0] = scale_bf8(*(const bf16x8*)(qr + 8 * g), QS);
    bqhi[1] = scale_bf8(*(const bf16x8*)(qr + 32 + 8 * g), QS);
  }

  float m_lo = -1e30f, m_hi = -1e30f;
  f32x4 o_lo[4] = {}, o_hi[4] = {};
  f32x4 o4_lo = {}, o4_hi = {};

  const int sR = w * 8 + (l >> 3);
  const int sc = l & 7;
  // V fragment base: lane (g,li) reads rows d = dn*16+li, cols kt*64 + kk*32 + 8g
  const unsigned short* vbase = vt + (long)(bh * 64 + li) * 2048 + 8 * g;

  int buf = 0;
  {
#pragma unroll
    for (int n = 0; n < 2; ++n) {
      int R = n * 32 + sR;
      int c = sc ^ (R & 7);
      gload_lds16(base + (long)R * 2304 + 768 + h * 64 + c * 8, &Ks[0][(n * 32 + w * 8) * 64]);
    }
  }
  __syncthreads();

  for (int kt = 0; kt <= qhi; ++kt) {
    // V fragments for this tile (global, L2-hit) -- issue FIRST (older than prefetch)
    bf16x8 vb[8];
#pragma unroll
    for (int kk = 0; kk < 2; ++kk)
#pragma unroll
      for (int dn = 0; dn < 4; ++dn)
        vb[kk * 4 + dn] = *(const bf16x8*)(vbase + (long)dn * 32768 + kt * 64 + kk * 32);

    if (kt < qhi) {
#pragma unroll
      for (int n = 0; n < 2; ++n) {
        int R = n * 32 + sR;
        int c = sc ^ (R & 7);
        gload_lds16(base + (long)((kt + 1) * 64 + R) * 2304 + 768 + h * 64 + c * 8,
                    &Ks[buf ^ 1][(n * 32 + w * 8) * 64]);
      }
    }
    attn_state(Ks[buf], vb, PsW, bqhi, kt == qhi, g, li, qloc, m_hi, o_hi, o4_hi);
    if (kt <= qlo)
      attn_state(Ks[buf], vb, PsW, bqlo, kt == qlo, g, li, qloc, m_lo, o_lo, o4_lo);
    __syncthreads();  // drains vmcnt (prefetch) + lgkm; protects buf swap
    buf ^= 1;
  }

#pragma unroll
  for (int t = 0; t < 2; ++t) {
    const f32x4* o = t ? o_hi : o_lo;
    const f32x4& o4 = t ? o4_hi : o4_lo;
    int qt = t ? qhi : qlo;
#pragma unroll
    for (int r = 0; r < 4; ++r) {
      float inv = 1.0f / o4[r];  // same q-domain as o: no shfl needed
      long row = (long)b * 2048 + qt * 64 + w * 16 + 4 * g + r;
#pragma unroll
      for (int dn = 0; dn < 4; ++dn)
        y[row * 768 + h * 64 + dn * 16 + li] = (unsigned short)f2bfbits(o[dn][r] * inv);
    }
  }
}

// ---------------- launch ----------------
extern "C" void kernel_launch(void* const* d_in, const int* in_sizes, int n_in,
                              void* d_out, int out_size, void* d_ws, size_t ws_size,
                              hipStream_t stream) {
  const float* x      = (const float*)d_in[0];
  const float* w_attn = (const float*)d_in[1];
  const float* b_attn = (const float*)d_in[2];
  const float* w_proj = (const float*)d_in[3];
  const float* b_proj = (const float*)d_in[4];
  float* out = (float*)d_out;

  unsigned short* xb   = (unsigned short*)d_ws;
  unsigned short* wab  = xb + 6291456;                  // 8192*768
  unsigned short* wpb  = wab + 1769472;                 // 2304*768
  unsigned short* qkvb = wpb + 589824;                  // 768*768
  unsigned short* yb   = qkvb + (long)8192 * 2304;
  unsigned short* vtb  = yb + 6291456;                  // 48*64*2048

  cvt3<<<8448, 256, 0, stream>>>(x, w_attn, w_proj, xb, wab, wpb);

  // QKV: 18x64 tiles -> 1152 blocks (8*144); x-inner XCD swizzle
  gemm_bt<unsigned short><<<1152, 256, 0, stream>>>(xb, wab, b_attn, qkvb, 8192, 2304, 768, 18, 144);
  transpose_v<<<1536, 64, 0, stream>>>(qkvb, vtb);
  attn_fwd<<<768, 256, 0, stream>>>(qkvb, vtb, yb);
  // proj: 6x64 tiles -> 384 blocks (8*48)
  gemm_bt<float><<<384, 256, 0, stream>>>(yb, wpb, b_proj, out, 8192, 768, 768, 6, 48);
}

// Round 15
// 127.347 us; speedup vs baseline: 3.0384x; 1.5043x over previous
//
#include <hip/hip_runtime.h>
#include <hip/hip_bf16.h>

// Fused CausalSelfAttention: x @ Wa^T + ba -> split heads -> causal flash attn
// -> y @ Wp^T + bp.  B=4, T=2048, C=768, H=12, hs=64.  bf16 MFMA, fp32 accum.
//
// ws (shorts): xb[8192*768] wab[2304*768] wpb[768*768] qkvb[8192*2304] yb[8192*768]
//              vtb[48*64*2048]  (~80 MB)

typedef __attribute__((ext_vector_type(8))) short bf16x8;
typedef __attribute__((ext_vector_type(4))) short bf16x4;
typedef __attribute__((ext_vector_type(4))) float f32x4;

#define MFMA16(a, b, c) __builtin_amdgcn_mfma_f32_16x16x32_bf16((a), (b), (c), 0, 0, 0)

__device__ __forceinline__ unsigned short f2bfbits(float f) {
  return __builtin_bit_cast(unsigned short, __float2bfloat16(f));
}
__device__ __forceinline__ float bf2f(short b) {
  return __uint_as_float(((unsigned)(unsigned short)b) << 16);
}
__device__ __forceinline__ float fast_exp2(float x) {
#if __has_builtin(__builtin_amdgcn_exp2f)
  return __builtin_amdgcn_exp2f(x);
#else
  return __expf(x * 0.6931471805599453f);
#endif
}
__device__ __forceinline__ float fmax3(float a, float b, float c) {
  return fmaxf(fmaxf(a, b), c);  // clang fuses to v_max3_f32
}
// truncation-pack two fp32 -> one u32 of 2 bf16 (RTZ; P is ratio-normalized so bias cancels)
__device__ __forceinline__ unsigned pk2bf(float lo, float hi) {
  return (__builtin_bit_cast(unsigned, hi) & 0xffff0000u) |
         (__builtin_bit_cast(unsigned, lo) >> 16);
}

__device__ __forceinline__ void gload_lds16(const void* g, void* l) {
  __builtin_amdgcn_global_load_lds((const __attribute__((address_space(1))) void*)g,
                                   (__attribute__((address_space(3))) void*)l, 16, 0, 0);
}

// ---------------- fp32 -> bf16 convert (x, w_attn, w_proj fused) ----------------
__global__ __launch_bounds__(256) void cvt3(const float* __restrict__ x,
                                            const float* __restrict__ wa,
                                            const float* __restrict__ wp,
                                            unsigned short* __restrict__ xb,
                                            unsigned short* __restrict__ wab,
                                            unsigned short* __restrict__ wpb) {
  int i = blockIdx.x * 256 + threadIdx.x;
  const float* in;
  unsigned short* out;
  int j;
  if (i < 1572864) { in = x; out = xb; j = i; }
  else if (i < 2015232) { in = wa; out = wab; j = i - 1572864; }
  else { in = wp; out = wpb; j = i - 2015232; }
  float4 f = ((const float4*)in)[j];
  bf16x4 o;
  o[0] = (short)f2bfbits(f.x); o[1] = (short)f2bfbits(f.y);
  o[2] = (short)f2bfbits(f.z); o[3] = (short)f2bfbits(f.w);
  ((bf16x4*)out)[j] = o;
}

// ---------------- GEMM 128x128 (m97 + chunk-XOR swizzle + T1 XCD block swizzle) ----------------
// 1D grid (nwg = 8*cpx), swz = (bid&7)*cpx + bid>>3; bx = swz % nx (x-inner).
template <typename OutT>
__global__ __launch_bounds__(256) void gemm_bt(const unsigned short* __restrict__ A,
                                               const unsigned short* __restrict__ Bt,
                                               const float* __restrict__ bias,
                                               OutT* __restrict__ C, int M, int N, int K,
                                               int nx, int cpx) {
  __shared__ unsigned short As[128 * 64];
  __shared__ unsigned short Bs[128 * 64];
  const int tid = threadIdx.x;
  const int w = tid >> 6, l = tid & 63;
  const int g = l >> 4, li = l & 15;
  const int wm = w >> 1, wn = w & 1;

  const int bid = blockIdx.x;
  const int swz = (bid & 7) * cpx + (bid >> 3);   // bijective (nwg % 8 == 0)
  const int bx = swz % nx, by = swz / nx;
  const int m0 = by * 128, n0 = bx * 128;

  const int scw = (l & 7) ^ ((l >> 3) & 7);
  const int swr = li & 7;

  f32x4 acc[4][4] = {};

  for (int kt = 0; kt < K; kt += 64) {
#pragma unroll
    for (int n = 0; n < 4; ++n) {
      int R = w * 32 + n * 8 + (l >> 3);
      gload_lds16(A + (long)(m0 + R) * K + kt + scw * 8, &As[(w * 32 + n * 8) * 64]);
      gload_lds16(Bt + (long)(n0 + R) * K + kt + scw * 8, &Bs[(w * 32 + n * 8) * 64]);
    }
    __syncthreads();
#pragma unroll
    for (int kk = 0; kk < 2; ++kk) {
      bf16x8 a[4], b[4];
#pragma unroll
      for (int m = 0; m < 4; ++m)
        a[m] = *(const bf16x8*)&As[(wm * 64 + m * 16 + li) * 64 + ((kk * 4 + g) ^ swr) * 8];
#pragma unroll
      for (int n = 0; n < 4; ++n)
        b[n] = *(const bf16x8*)&Bs[(wn * 64 + n * 16 + li) * 64 + ((kk * 4 + g) ^ swr) * 8];
#pragma unroll
      for (int m = 0; m < 4; ++m)
#pragma unroll
        for (int n = 0; n < 4; ++n) acc[m][n] = MFMA16(a[m], b[n], acc[m][n]);
    }
    __syncthreads();
  }

#pragma unroll
  for (int m = 0; m < 4; ++m) {
    int row = m0 + wm * 64 + m * 16 + 4 * g;
#pragma unroll
    for (int n = 0; n < 4; ++n) {
      int col = n0 + wn * 64 + n * 16 + li;
      float bi = bias[col];
#pragma unroll
      for (int r = 0; r < 4; ++r) {
        float v = acc[m][n][r] + bi;
        if constexpr (sizeof(OutT) == 2)
          C[(long)(row + r) * N + col] = (OutT)f2bfbits(v);
        else
          C[(long)(row + r) * N + col] = v;
      }
    }
  }
}

// ---------------- GEMM 64(M)x128(N) tile: tail-free variant for the proj GEMM ----------------
// 4 waves as 1(M)x4(N); per wave 64x32 output (acc[4][2]).  Same swizzle invariants:
// read rows = {m*16+li, w*32+n*16+li} are ≡ li (mod 8); staging rows ≡ l>>3 (mod 8).
template <typename OutT>
__global__ __launch_bounds__(256) void gemm_bt64(const unsigned short* __restrict__ A,
                                                 const unsigned short* __restrict__ Bt,
                                                 const float* __restrict__ bias,
                                                 OutT* __restrict__ C, int M, int N, int K,
                                                 int nx, int cpx) {
  __shared__ unsigned short As[64 * 64];     // 8 KB
  __shared__ unsigned short Bs[128 * 64];    // 16 KB
  const int tid = threadIdx.x;
  const int w = tid >> 6, l = tid & 63;
  const int g = l >> 4, li = l & 15;

  const int bid = blockIdx.x;
  const int swz = (bid & 7) * cpx + (bid >> 3);   // bijective (nwg % 8 == 0)
  const int bx = swz % nx, by = swz / nx;
  const int m0 = by * 64, n0 = bx * 128;

  const int scw = (l & 7) ^ ((l >> 3) & 7);
  const int swr = li & 7;

  f32x4 acc[4][2] = {};

  for (int kt = 0; kt < K; kt += 64) {
#pragma unroll
    for (int n = 0; n < 2; ++n) {
      int R = w * 16 + n * 8 + (l >> 3);
      gload_lds16(A + (long)(m0 + R) * K + kt + scw * 8, &As[(w * 16 + n * 8) * 64]);
    }
#pragma unroll
    for (int n = 0; n < 4; ++n) {
      int R = w * 32 + n * 8 + (l >> 3);
      gload_lds16(Bt + (long)(n0 + R) * K + kt + scw * 8, &Bs[(w * 32 + n * 8) * 64]);
    }
    __syncthreads();
#pragma unroll
    for (int kk = 0; kk < 2; ++kk) {
      bf16x8 a[4], b[2];
#pragma unroll
      for (int m = 0; m < 4; ++m)
        a[m] = *(const bf16x8*)&As[(m * 16 + li) * 64 + ((kk * 4 + g) ^ swr) * 8];
#pragma unroll
      for (int n = 0; n < 2; ++n)
        b[n] = *(const bf16x8*)&Bs[(w * 32 + n * 16 + li) * 64 + ((kk * 4 + g) ^ swr) * 8];
#pragma unroll
      for (int m = 0; m < 4; ++m)
#pragma unroll
        for (int n = 0; n < 2; ++n) acc[m][n] = MFMA16(a[m], b[n], acc[m][n]);
    }
    __syncthreads();
  }

#pragma unroll
  for (int m = 0; m < 4; ++m) {
    int row = m0 + m * 16 + 4 * g;
#pragma unroll
    for (int n = 0; n < 2; ++n) {
      int col = n0 + w * 32 + n * 16 + li;
      float bi = bias[col];
#pragma unroll
      for (int r = 0; r < 4; ++r) {
        float v = acc[m][n][r] + bi;
        if constexpr (sizeof(OutT) == 2)
          C[(long)(row + r) * N + col] = (OutT)f2bfbits(v);
        else
          C[(long)(row + r) * N + col] = v;
      }
    }
  }
}

// ---------------- V transpose: qkv V-part -> Vt[bh][d][t] ----------------
__global__ __launch_bounds__(64) void transpose_v(const unsigned short* __restrict__ qkv,
                                                  unsigned short* __restrict__ vt) {
  const int kt = blockIdx.x & 31, bh = blockIdx.x >> 5;
  const int b = bh / 12, h = bh - b * 12;
  const int l = threadIdx.x;
  const int ct = l & 7, cd = l >> 3;

  bf16x8 tin[8], tout[8];
#pragma unroll
  for (int i = 0; i < 8; ++i)
    tin[i] = *(const bf16x8*)(qkv + (long)(b * 2048 + kt * 64 + ct * 8 + i) * 2304 +
                              1536 + h * 64 + cd * 8);
#pragma unroll
  for (int j = 0; j < 8; ++j) {
#pragma unroll
    for (int i = 0; i < 8; ++i) tout[j][i] = tin[i][j];
    *(bf16x8*)(vt + (long)(bh * 64 + cd * 8 + j) * 2048 + kt * 64 + ct * 8) = tout[j];
  }
}

// ---------------- attention helpers ----------------
__device__ __forceinline__ bf16x8 scale_bf8(bf16x8 v, float c) {
  bf16x8 o;
#pragma unroll
  for (int j = 0; j < 8; ++j) o[j] = (short)f2bfbits(bf2f(v[j]) * c);
  return o;
}

// softmax of one 64(k)x16(q) S^T state (log2 domain); P (bf16, RTZ) -> LDS.
// Row-sum l comes from the ones-column MFMA in PV (o4).
__device__ __forceinline__ void softmax_state(f32x4* s, bool diag, int g, int li, int qloc,
                                              unsigned short* PsW, float& m, f32x4* o,
                                              f32x4& o4) {
  if (diag) {
#pragma unroll
    for (int kn = 0; kn < 4; ++kn)
#pragma unroll
      for (int r = 0; r < 4; ++r)
        if (kn * 16 + 4 * g + r > qloc) s[kn][r] = -1e30f;
  }
  float a = fmax3(s[0][0], s[0][1], s[0][2]);
  float b = fmax3(s[0][3], s[1][0], s[1][1]);
  float c = fmax3(s[1][2], s[1][3], s[2][0]);
  float d = fmax3(s[2][1], s[2][2], s[2][3]);
  float e = fmax3(s[3][0], s[3][1], s[3][2]);
  float pm = fmaxf(fmax3(a, b, c), fmax3(d, e, s[3][3]));
  pm = fmaxf(pm, __shfl_xor(pm, 16));
  pm = fmaxf(pm, __shfl_xor(pm, 32));

  if (!__all(pm - m <= 10.0f)) {  // defer-max (T13): rescale only on real growth
    float mn = fmaxf(m, pm);
    float alpha = fast_exp2(m - mn);
    m = mn;
    float alo[4];
#pragma unroll
    for (int r = 0; r < 4; ++r) alo[r] = __shfl(alpha, 20 * g + r);
#pragma unroll
    for (int dn = 0; dn < 4; ++dn)
#pragma unroll
      for (int r = 0; r < 4; ++r) o[dn][r] *= alo[r];
#pragma unroll
    for (int r = 0; r < 4; ++r) o4[r] *= alo[r];
  }

  const int swp = li & 7;
#pragma unroll
  for (int kn = 0; kn < 4; ++kn) {
    float e0 = fast_exp2(s[kn][0] - m);
    float e1 = fast_exp2(s[kn][1] - m);
    float e2 = fast_exp2(s[kn][2] - m);
    float e3 = fast_exp2(s[kn][3] - m);
    uint2 pk = {pk2bf(e0, e1), pk2bf(e2, e3)};
    *(uint2*)&PsW[li * 64 + ((kn * 2 + (g >> 1)) ^ swp) * 8 + (g & 1) * 4] = pk;
  }
}

// one full state: QK -> softmax -> PV.  Uses the wave's single P buffer; same-wave
// LDS ops are in-order, so sm's ds_write is seen by PV's ds_read without a fence.
// Keeping QK/sm/PV per-state means at most one 16-reg S block is live at any time.
__device__ __forceinline__ void attn_state(const unsigned short* Ks, const unsigned short* Vs,
                                           unsigned short* PsW, const bf16x8* bq, bool diag,
                                           int g, int li, int qloc,
                                           float& m, f32x4* o, f32x4& o4) {
  f32x4 s[4];
  __builtin_amdgcn_s_setprio(1);
#pragma unroll
  for (int kn = 0; kn < 4; ++kn) {
    int rr = kn * 16 + li, sw = rr & 7;
    f32x4 acc = {};
#pragma unroll
    for (int kk = 0; kk < 2; ++kk) {
      bf16x8 ak = *(const bf16x8*)&Ks[rr * 64 + ((kk * 4 + g) ^ sw) * 8];
      acc = MFMA16(ak, bq[kk], acc);
    }
    s[kn] = acc;
  }
  __builtin_amdgcn_s_setprio(0);

  softmax_state(s, diag, g, li, qloc, PsW, m, o, o4);

  bf16x8 vones;
#pragma unroll
  for (int j = 0; j < 8; ++j) vones[j] = (short)0x3F80;
  const int swp = li & 7;
  __builtin_amdgcn_s_setprio(1);
#pragma unroll
  for (int kk = 0; kk < 2; ++kk) {
    bf16x8 pa = *(const bf16x8*)&PsW[li * 64 + ((kk * 4 + g) ^ swp) * 8];
#pragma unroll
    for (int dn = 0; dn < 4; ++dn) {
      // (dn*16+li)&7 == li&7: V rows share the same swizzle key
      bf16x8 vb = *(const bf16x8*)&Vs[(dn * 16 + li) * 64 + ((kk * 4 + g) ^ swp) * 8];
      o[dn] = MFMA16(pa, vb, o[dn]);
    }
    o4 = MFMA16(pa, vones, o4);   // row-sum l via ones column
  }
  __builtin_amdgcn_s_setprio(0);
}

// ---------------- causal flash attention (paired q-tiles, dual-state) ----------------
// p-decorrelation: co-CU blocks (slots s, s+32, s+64) get p spreads {a, a+11, a+6}
// so long pairs co-reside with short ones (bijective per bh: slot>>5 fixed for slot>>4).
__global__ __launch_bounds__(256, 3) void attn_fwd(const unsigned short* __restrict__ qkv,
                                                   const unsigned short* __restrict__ vt,
                                                   unsigned short* __restrict__ y) {
  const int xcd = blockIdx.x & 7;
  const int slot = blockIdx.x >> 3;                       // 0..95
  const int bh = xcd * 6 + (slot >> 4);                   // XCD-local bh (L2 locality)
  const int p = ((slot & 15) + 11 * (slot >> 5)) & 15;    // decorrelated pair index
  const int b = bh / 12, h = bh - b * 12;
  const int qlo = p, qhi = 31 - p;
  const int tid = threadIdx.x;
  const int w = tid >> 6, l = tid & 63;
  const int g = l >> 4, li = l & 15;
  const int qloc = w * 16 + li;

  __shared__ unsigned short Ks[2][64 * 64];
  __shared__ unsigned short Vs[2][64 * 64];
  __shared__ unsigned short Ps[4][16 * 64];   // ONE buffer per wave -> 40 KB, 4 blocks/CU
  unsigned short* PsW = &Ps[w][0];

  const unsigned short* base = qkv + (long)b * 2048 * 2304;

  // Q fragments (B-operand), pre-scaled by 0.125*log2(e) -> softmax in exp2 domain
  const float QS = 0.18033688011112042f;
  bf16x8 bqlo[2], bqhi[2];
  {
    const unsigned short* qr = base + (long)(qlo * 64 + qloc) * 2304 + h * 64;
    bqlo[0] = scale_bf8(*(const bf16x8*)(qr + 8 * g), QS);
    bqlo[1] = scale_bf8(*(const bf16x8*)(qr + 32 + 8 * g), QS);
    qr = base + (long)(qhi * 64 + qloc) * 2304 + h * 64;
    bqhi[0] = scale_bf8(*(const bf16x8*)(qr + 8 * g), QS);
    bqhi[1] = scale_bf8(*(const bf16x8*)(qr + 32 + 8 * g), QS);
  }

  float m_lo = -1e30f, m_hi = -1e30f;
  f32x4 o_lo[4] = {}, o_hi[4] = {};
  f32x4 o4_lo = {}, o4_hi = {};

  const int sR = w * 8 + (l >> 3);
  const int sc = l & 7;

  int buf = 0;
  {
#pragma unroll
    for (int n = 0; n < 2; ++n) {
      int R = n * 32 + sR;
      int c = sc ^ (R & 7);
      gload_lds16(base + (long)R * 2304 + 768 + h * 64 + c * 8, &Ks[0][(n * 32 + w * 8) * 64]);
      gload_lds16(vt + (long)(bh * 64 + R) * 2048 + c * 8, &Vs[0][(n * 32 + w * 8) * 64]);
    }
  }
  __syncthreads();

  for (int kt = 0; kt <= qhi; ++kt) {
    if (kt < qhi) {
#pragma unroll
      for (int n = 0; n < 2; ++n) {
        int R = n * 32 + sR;
        int c = sc ^ (R & 7);
        gload_lds16(base + (long)((kt + 1) * 64 + R) * 2304 + 768 + h * 64 + c * 8,
                    &Ks[buf ^ 1][(n * 32 + w * 8) * 64]);
        gload_lds16(vt + (long)(bh * 64 + R) * 2048 + (kt + 1) * 64 + c * 8,
                    &Vs[buf ^ 1][(n * 32 + w * 8) * 64]);
      }
    }
    attn_state(Ks[buf], Vs[buf], PsW, bqhi, kt == qhi, g, li, qloc, m_hi, o_hi, o4_hi);
    if (kt <= qlo)
      attn_state(Ks[buf], Vs[buf], PsW, bqlo, kt == qlo, g, li, qloc, m_lo, o_lo, o4_lo);
    __syncthreads();  // drains vmcnt (prefetch) + lgkm; protects buf swap
    buf ^= 1;
  }

#pragma unroll
  for (int t = 0; t < 2; ++t) {
    const f32x4* o = t ? o_hi : o_lo;
    const f32x4& o4 = t ? o4_hi : o4_lo;
    int qt = t ? qhi : qlo;
#pragma unroll
    for (int r = 0; r < 4; ++r) {
      float inv = 1.0f / o4[r];  // same q-domain as o: no shfl needed
      long row = (long)b * 2048 + qt * 64 + w * 16 + 4 * g + r;
#pragma unroll
      for (int dn = 0; dn < 4; ++dn)
        y[row * 768 + h * 64 + dn * 16 + li] = (unsigned short)f2bfbits(o[dn][r] * inv);
    }
  }
}

// ---------------- launch ----------------
extern "C" void kernel_launch(void* const* d_in, const int* in_sizes, int n_in,
                              void* d_out, int out_size, void* d_ws, size_t ws_size,
                              hipStream_t stream) {
  const float* x      = (const float*)d_in[0];
  const float* w_attn = (const float*)d_in[1];
  const float* b_attn = (const float*)d_in[2];
  const float* w_proj = (const float*)d_in[3];
  const float* b_proj = (const float*)d_in[4];
  float* out = (float*)d_out;

  unsigned short* xb   = (unsigned short*)d_ws;
  unsigned short* wab  = xb + 6291456;                  // 8192*768
  unsigned short* wpb  = wab + 1769472;                 // 2304*768
  unsigned short* qkvb = wpb + 589824;                  // 768*768
  unsigned short* yb   = qkvb + (long)8192 * 2304;
  unsigned short* vtb  = yb + 6291456;                  // 48*64*2048

  cvt3<<<8448, 256, 0, stream>>>(x, w_attn, w_proj, xb, wab, wpb);

  // QKV: 18x64 tiles -> 1152 blocks (8*144); x-inner XCD swizzle
  gemm_bt<unsigned short><<<1152, 256, 0, stream>>>(xb, wab, b_attn, qkvb, 8192, 2304, 768, 18, 144);
  transpose_v<<<1536, 64, 0, stream>>>(qkvb, vtb);
  attn_fwd<<<768, 256, 0, stream>>>(qkvb, vtb, yb);
  // proj: 64x128 tiles -> 128x6 = 768 blocks (8*96) -> 3 blocks/CU, no tail
  gemm_bt64<float><<<768, 256, 0, stream>>>(yb, wpb, b_proj, out, 8192, 768, 768, 6, 96);
}